// Round 3
// 1818.509 us; speedup vs baseline: 1.0305x; 1.0305x over previous
//
#include <hip/hip_runtime.h>
#include <hip/hip_bf16.h>

// LSTM B=1024 T=256 IN=64 H=512. Round 8: R7 flag-exchange protocol plus a
// hang-proof watchdog on the poll loop (2^16 spins ~ 20ms >> expected ~5us;
// on timeout fall through instead of wedging the GPU -> a latent sync bug
// surfaces as passed:false instead of a dead container).
// Protocol recap (vs R6's centralized counter barrier):
//   producer: h stores -> __syncthreads (vmcnt drain => stores acked at the
//             coherence point, same property R6 relied on) -> flag[jb]=t+1
//   consumer: wave-level poll of all 8 flags (lanes 0..7, one MALL rtt per
//             poll round), overlapped with the x_t global loads; then the
//             16x8B agent h-loads issue immediately (no barrier between
//             poll and load -- the polling wave IS the loading wave).
// Removes one agent RMW round-trip + counter contention + one syncthreads
// per step (3 -> 2) and hides flag-detection latency under x staging.
// 3-buffer rotation safety: a block reaches step t+2 only after all flags
// >= t+2, and flag t+2 is set only after that producer finished READING
// h(t+1), so overwriting buffer (t+2)%3 == (t-1)%3 cannot race a reader.
// Everything else unchanged from R6: 32 m-groups x 8 j-blocks, persistent
// 256 blocks (1/CU), register-resident f16 weights, single-phase A staging
// (37KB LDS), 1 A-read feeds 2 MFMAs, DPP epilogue (quad_perm gate combine
// + row_shl pack).

#define TST   256
#define BATCH 1024
#define HID   512
#define INSZ  64
#define NCLS  10
#define LDSTR 584   // elem stride: 1168 B = 292 dw = 4 mod 32 -> conflict-free

typedef _Float16 f16x8  __attribute__((ext_vector_type(8)));
typedef float    f32x16 __attribute__((ext_vector_type(16)));
typedef unsigned long long u64;

__device__ __forceinline__ float tanh_f(float x) {
    return 2.0f / (1.0f + __expf(-2.0f * x)) - 1.0f;
}

__device__ __forceinline__ f16x8 cvt8(float4 a, float4 b) {
    f16x8 o;
    o[0] = (_Float16)a.x; o[1] = (_Float16)a.y; o[2] = (_Float16)a.z; o[3] = (_Float16)a.w;
    o[4] = (_Float16)b.x; o[5] = (_Float16)b.y; o[6] = (_Float16)b.z; o[7] = (_Float16)b.w;
    return o;
}

__device__ __forceinline__ u64 cvt4_u64(float4 a) {
    _Float16 h[4] = {(_Float16)a.x, (_Float16)a.y, (_Float16)a.z, (_Float16)a.w};
    u64 r;
    __builtin_memcpy(&r, h, 8);
    return r;
}

template <int CTRL>
__device__ __forceinline__ float dpp_f(float v) {
    return __builtin_bit_cast(float,
        __builtin_amdgcn_mov_dpp(__builtin_bit_cast(int, v), CTRL, 0xF, 0xF, true));
}
template <int CTRL>
__device__ __forceinline__ unsigned dpp_u(unsigned v) {
    return (unsigned)__builtin_amdgcn_mov_dpp((int)v, CTRL, 0xF, 0xF, true);
}
// DPP ctrls: quad_perm xor1=0xB1, xor2=0x4E, xor3=0x1B (symmetric);
// row_shl:4=0x104, row_shl:8=0x108 (dst lane i <- src lane i+N).

__global__ __launch_bounds__(256, 1) void lstm_persist(
    const float* __restrict__ x,   const float* __restrict__ h0,
    const float* __restrict__ c0,  const float* __restrict__ Wih,
    const float* __restrict__ Whh, const float* __restrict__ bih,
    const float* __restrict__ bhh, _Float16* __restrict__ hb,
    unsigned* __restrict__ bar)
{
    __shared__ __align__(16) _Float16 As[32][LDSTR];   // 37376 B

    const int tid   = threadIdx.x;
    const int lane  = tid & 63;
    const int w     = tid >> 6;        // wave 0..3
    const int l31   = lane & 31;
    const int khalf = (lane >> 5) * 8;
    const int g  = (int)(blockIdx.x >> 3);   // m-group 0..31
    const int jb = (int)(blockIdx.x & 7);    // j-block 0..7
    const int m0 = g * 32;
    const int j0 = jb * 64;
    // 8 release flags per group, 32B apart (256B/group, 8KB total, memset 0)
    unsigned* flg = bar + g * 64;

    const int gate = l31 & 3;                // nt*32 preserves np&3
    int jcol[2], nrow[2];
    #pragma unroll
    for (int nt = 0; nt < 2; ++nt) {
        int np = w * 64 + nt * 32 + l31;
        jcol[nt] = j0 + (np >> 2);
        nrow[nt] = gate * HID + jcol[nt];
    }

    // ---- B fragments in registers (one-time): bfr[nt][kt] ----
    f16x8 bfr[2][36];
    #pragma unroll
    for (int nt = 0; nt < 2; ++nt)
        #pragma unroll
        for (int kt = 0; kt < 36; ++kt) {
            const int k0 = kt * 16 + khalf;
            const float* p = (kt < 32) ? (Whh + (size_t)nrow[nt] * HID + k0)
                                       : (Wih + (size_t)nrow[nt] * INSZ + (k0 - HID));
            float4 f0 = ((const float4*)p)[0];
            float4 f1 = ((const float4*)p)[1];
            bfr[nt][kt] = cvt8(f0, f1);
        }
    float bsv[2];
    bsv[0] = bih[nrow[0]] + bhh[nrow[0]];
    bsv[1] = bih[nrow[1]] + bhh[nrow[1]];
    const float s   = (gate == 2) ? 2.0f : 1.0f;   // tanh for g, sigmoid otherwise
    const int rowhi = (lane >> 5) * 4;

    // ---- c state in registers (lead lanes l31%4==0 hold the real values) ----
    float cr[2][16];
    #pragma unroll
    for (int nt = 0; nt < 2; ++nt)
        #pragma unroll
        for (int r = 0; r < 16; ++r) {
            int row = (r & 3) + 8 * (r >> 2) + rowhi;
            cr[nt][r] = c0[(size_t)(m0 + row) * HID + jcol[nt]];
        }

    const int rr = tid >> 3;       // staging: 8 threads per row (32 rows)
    const int q  = tid & 7;

    for (int t = 0; t < TST; ++t) {
        const _Float16* rb = hb + (size_t)((t + 2) % 3) * (BATCH * HID);
        _Float16*       wb = hb + (size_t)(t % 3) * (BATCH * HID);

        // ---- issue x loads first: their latency hides under the flag poll ----
        float4 x0, x1;
        {
            const float* xp = x + (size_t)(m0 + rr) * (TST * INSZ) + t * INSZ + q * 8;
            x0 = ((const float4*)xp)[0];
            x1 = ((const float4*)xp)[1];
        }
        if (t == 0) {
            u64 hv[16];
            #pragma unroll
            for (int u = 0; u < 16; ++u) {
                float4 f = *(const float4*)(h0 + (size_t)(m0 + rr) * HID + q * 4 + u * 32);
                hv[u] = cvt4_u64(f);
            }
            #pragma unroll
            for (int u = 0; u < 16; ++u)
                *(u64*)&As[rr][q * 4 + u * 32] = hv[u];
        } else {
            // ---- wave-level poll: lanes 0..7 each watch one producer flag.
            // Producers set flag = t at the end of step t-1. Watchdog: cap
            // the spin at 2^16 iterations (~20ms >> expected ~5us) so a
            // latent sync bug can never wedge the GPU; fallthrough surfaces
            // as a wrong-answer diagnostic instead of a dead container.
            const unsigned tgt = (unsigned)t;
            int spins = 0;
            while (true) {
                unsigned v = tgt;
                if (lane < 8)
                    v = __hip_atomic_load(flg + lane * 8,
                                          __ATOMIC_RELAXED, __HIP_MEMORY_SCOPE_AGENT);
                if (__all((int)(v >= tgt))) break;
                if (++spins > (1 << 16)) break;   // watchdog (never in practice)
                __builtin_amdgcn_s_sleep(1);
            }
            __atomic_signal_fence(__ATOMIC_SEQ_CST);  // compiler fence: no load hoisting
            // coherent (sc0 sc1) 8B loads from the MALL — data was acked at the
            // coherence point before the flag was set, so these return fresh h.
            const u64* rbq = (const u64*)(rb + (size_t)(m0 + rr) * HID);
            u64 hv[16];
            #pragma unroll
            for (int u = 0; u < 16; ++u)
                hv[u] = __hip_atomic_load(&rbq[q + u * 8],
                                          __ATOMIC_RELAXED, __HIP_MEMORY_SCOPE_AGENT);
            #pragma unroll
            for (int u = 0; u < 16; ++u)
                *(u64*)&As[rr][q * 4 + u * 32] = hv[u];
        }
        *(f16x8*)&As[rr][512 + q * 8] = cvt8(x0, x1);   // x_t -> k 512..575
        __syncthreads();

        // ---- MFMA: 36 k-tiles, 1 A-read feeds both n-tiles ----
        f32x16 acc[2];
        #pragma unroll
        for (int i = 0; i < 16; ++i) { acc[0][i] = 0.0f; acc[1][i] = 0.0f; }
        #pragma unroll
        for (int kt = 0; kt < 36; ++kt) {
            f16x8 af = *(const f16x8*)&As[l31][kt * 16 + khalf];
            acc[0] = __builtin_amdgcn_mfma_f32_32x32x16_f16(af, bfr[0][kt], acc[0], 0, 0, 0);
            acc[1] = __builtin_amdgcn_mfma_f32_32x32x16_f16(af, bfr[1][kt], acc[1], 0, 0, 0);
        }

        // ---- epilogue: DPP gate combine (VALU, no DS), c/h update, 8B stores ----
        #pragma unroll
        for (int nt = 0; nt < 2; ++nt) {
            #pragma unroll
            for (int r = 0; r < 16; ++r) {
                float v = acc[nt][r] + bsv[nt];
                float e = __expf(-s * v);
                float act = s / (1.0f + e) - (s - 1.0f);   // sigmoid or tanh
                float fu = dpp_f<0xB1>(act);   // quad xor1: f
                float gu = dpp_f<0x4E>(act);   // quad xor2: g
                float ou = dpp_f<0x1B>(act);   // quad xor3: o
                float cn = fu * cr[nt][r] + act * gu;
                cr[nt][r] = cn;
                float hn = ou * tanh_f(cn);
                unsigned hu = (unsigned)__builtin_bit_cast(unsigned short, (_Float16)hn);
                unsigned pk = hu | (dpp_u<0x104>(hu) << 16);          // <- lane+4
                u64 v4 = (u64)pk | ((u64)dpp_u<0x108>(pk) << 32);     // <- lane+8
                if ((l31 & 15) == 0) {
                    int row = (r & 3) + 8 * (r >> 2) + rowhi;
                    __hip_atomic_store((u64*)&wb[(size_t)(m0 + row) * HID + jcol[nt]],
                                       v4, __ATOMIC_RELAXED, __HIP_MEMORY_SCOPE_AGENT);
                }
            }
        }

        // ---- release: drain stores (syncthreads emits vmcnt(0) before the
        // barrier => all 4 waves' h stores acked), then publish flag ----
        __syncthreads();
        if (tid == 0)
            __hip_atomic_store(flg + jb * 8, (unsigned)(t + 1),
                               __ATOMIC_RELAXED, __HIP_MEMORY_SCOPE_AGENT);
    }
}

// ---------------- final linear: preds = hT @ W_lin^T + b_lin ----------------
__global__ __launch_bounds__(256) void final_kernel(
    const _Float16* __restrict__ h, const float* __restrict__ Wl,
    const float* __restrict__ bl, float* __restrict__ out)
{
    int i = blockIdx.x * 256 + threadIdx.x;
    if (i >= BATCH * NCLS) return;
    int b = i / NCLS, c = i - b * NCLS;
    const f16x8* hp = (const f16x8*)(h + (size_t)b * HID);
    const float4* wp = (const float4*)(Wl + (size_t)c * HID);
    float sacc = bl[c];
    #pragma unroll 4
    for (int k8 = 0; k8 < HID / 8; ++k8) {
        f16x8 hv = hp[k8];
        float4 w0 = wp[2 * k8], w1 = wp[2 * k8 + 1];
        sacc += (float)hv[0] * w0.x + (float)hv[1] * w0.y +
                (float)hv[2] * w0.z + (float)hv[3] * w0.w +
                (float)hv[4] * w1.x + (float)hv[5] * w1.y +
                (float)hv[6] * w1.z + (float)hv[7] * w1.w;
    }
    out[i] = sacc;
}

extern "C" void kernel_launch(void* const* d_in, const int* in_sizes, int n_in,
                              void* d_out, int out_size, void* d_ws, size_t ws_size,
                              hipStream_t stream)
{
    const float* x    = (const float*)d_in[0];
    const float* h0   = (const float*)d_in[1];
    const float* c0   = (const float*)d_in[2];
    const float* Wih  = (const float*)d_in[3];
    const float* Whh  = (const float*)d_in[4];
    const float* bih  = (const float*)d_in[5];
    const float* bhh  = (const float*)d_in[6];
    const float* Wlin = (const float*)d_in[7];
    const float* blin = (const float*)d_in[8];
    float* out = (float*)d_out;

    unsigned* bar = (unsigned*)d_ws;                   // 32 groups x 8 flags, 32B apart
    _Float16* hb  = (_Float16*)((char*)d_ws + 8192);   // 3 x 1 MB h buffers

    hipMemsetAsync(d_ws, 0, 8192, stream);             // zero release flags

    // 256 blocks, 1/CU (launch_bounds(256,1), 37KB LDS) -> all co-resident.
    lstm_persist<<<256, 256, 0, stream>>>(x, h0, c0, Wih, Whh, bih, bhh, hb, bar);

    // step t=255 wrote buffer (255 % 3) == 0 -> hb
    final_kernel<<<(BATCH * NCLS + 255) / 256, 256, 0, stream>>>(hb, Wlin, blin, out);
}

// Round 4
// 1714.552 us; speedup vs baseline: 1.0930x; 1.0606x over previous
//
#include <hip/hip_runtime.h>
#include <hip/hip_bf16.h>

// LSTM B=1024 T=256 IN=64 H=512. Round 9: two changes vs R8 (1818us):
// (1) fast reciprocal: both IEEE divisions in the epilogue (act = s/(1+e),
//     tanh = 2/(1+e)-1) replaced by v_rcp_f32 (~1 ulp; f16 output tolerance
//     dwarfs the error). Kills ~10 instr incl. transcendental-rate div
//     helpers per division per r-iter (~0.35us/step of VALU).
// (2) per-wave release flags: the release __syncthreads is GONE. Each wave
//     drains its own h-stores (s_waitcnt vmcnt(0), inline asm) and publishes
//     its own flag (jb*4+w) -> 32 flags per m-group, packed 4B apart so the
//     whole set is one 128B line (one MALL fetch per poll round, lanes 0..31
//     poll one flag each). Flags double as the intra-block LDS-reuse token:
//     poll-pass => all local waves published => finished epilogue stores =>
//     (acc <- MFMA <- ds_read dependence) finished all LDS reads of the
//     previous step => safe to overwrite As with no release barrier.
// One __syncthreads per step remains (post-staging join). Watchdog kept:
// poll falls through after 2^16 spins so a latent sync bug surfaces as
// passed:false, never a wedged container.
// 3-buffer rotation safety unchanged: a wave reaches step t+1 only after
// all 32 group flags >= t+1, so skew <= 1 step and the (t+2)%3 read buffer
// can never be overwritten under a reader.
// Everything else unchanged from R6/R8: 32 m-groups x 8 j-blocks, persistent
// 256 blocks (1/CU), register-resident f16 weights, single-phase A staging
// (37KB LDS), 1 A-read feeds 2 MFMAs, DPP epilogue (quad_perm gate combine
// + row_shl pack).

#define TST   256
#define BATCH 1024
#define HID   512
#define INSZ  64
#define NCLS  10
#define LDSTR 584   // elem stride: 1168 B = 292 dw = 4 mod 32 -> conflict-free

typedef _Float16 f16x8  __attribute__((ext_vector_type(8)));
typedef float    f32x16 __attribute__((ext_vector_type(16)));
typedef unsigned long long u64;

__device__ __forceinline__ float fast_rcp(float x) {
    return __builtin_amdgcn_rcpf(x);   // v_rcp_f32, ~1 ulp
}

__device__ __forceinline__ float tanh_f(float x) {
    return 2.0f * fast_rcp(1.0f + __expf(-2.0f * x)) - 1.0f;
}

__device__ __forceinline__ f16x8 cvt8(float4 a, float4 b) {
    f16x8 o;
    o[0] = (_Float16)a.x; o[1] = (_Float16)a.y; o[2] = (_Float16)a.z; o[3] = (_Float16)a.w;
    o[4] = (_Float16)b.x; o[5] = (_Float16)b.y; o[6] = (_Float16)b.z; o[7] = (_Float16)b.w;
    return o;
}

__device__ __forceinline__ u64 cvt4_u64(float4 a) {
    _Float16 h[4] = {(_Float16)a.x, (_Float16)a.y, (_Float16)a.z, (_Float16)a.w};
    u64 r;
    __builtin_memcpy(&r, h, 8);
    return r;
}

template <int CTRL>
__device__ __forceinline__ float dpp_f(float v) {
    return __builtin_bit_cast(float,
        __builtin_amdgcn_mov_dpp(__builtin_bit_cast(int, v), CTRL, 0xF, 0xF, true));
}
template <int CTRL>
__device__ __forceinline__ unsigned dpp_u(unsigned v) {
    return (unsigned)__builtin_amdgcn_mov_dpp((int)v, CTRL, 0xF, 0xF, true);
}
// DPP ctrls: quad_perm xor1=0xB1, xor2=0x4E, xor3=0x1B (symmetric);
// row_shl:4=0x104, row_shl:8=0x108 (dst lane i <- src lane i+N).

__global__ __launch_bounds__(256, 1) void lstm_persist(
    const float* __restrict__ x,   const float* __restrict__ h0,
    const float* __restrict__ c0,  const float* __restrict__ Wih,
    const float* __restrict__ Whh, const float* __restrict__ bih,
    const float* __restrict__ bhh, _Float16* __restrict__ hb,
    unsigned* __restrict__ bar)
{
    __shared__ __align__(16) _Float16 As[32][LDSTR];   // 37376 B

    const int tid   = threadIdx.x;
    const int lane  = tid & 63;
    const int w     = tid >> 6;        // wave 0..3
    const int l31   = lane & 31;
    const int khalf = (lane >> 5) * 8;
    const int g  = (int)(blockIdx.x >> 3);   // m-group 0..31
    const int jb = (int)(blockIdx.x & 7);    // j-block 0..7
    const int m0 = g * 32;
    const int j0 = jb * 64;
    // 32 per-wave release flags per group (4B apart = one 128B line),
    // groups padded to 256B. 8KB total, memset 0.
    unsigned* flg = bar + g * 64;

    const int gate = l31 & 3;                // nt*32 preserves np&3
    int jcol[2], nrow[2];
    #pragma unroll
    for (int nt = 0; nt < 2; ++nt) {
        int np = w * 64 + nt * 32 + l31;
        jcol[nt] = j0 + (np >> 2);
        nrow[nt] = gate * HID + jcol[nt];
    }

    // ---- B fragments in registers (one-time): bfr[nt][kt] ----
    f16x8 bfr[2][36];
    #pragma unroll
    for (int nt = 0; nt < 2; ++nt)
        #pragma unroll
        for (int kt = 0; kt < 36; ++kt) {
            const int k0 = kt * 16 + khalf;
            const float* p = (kt < 32) ? (Whh + (size_t)nrow[nt] * HID + k0)
                                       : (Wih + (size_t)nrow[nt] * INSZ + (k0 - HID));
            float4 f0 = ((const float4*)p)[0];
            float4 f1 = ((const float4*)p)[1];
            bfr[nt][kt] = cvt8(f0, f1);
        }
    float bsv[2];
    bsv[0] = bih[nrow[0]] + bhh[nrow[0]];
    bsv[1] = bih[nrow[1]] + bhh[nrow[1]];
    const float s   = (gate == 2) ? 2.0f : 1.0f;   // tanh for g, sigmoid otherwise
    const int rowhi = (lane >> 5) * 4;

    // ---- c state in registers (lead lanes l31%4==0 hold the real values) ----
    float cr[2][16];
    #pragma unroll
    for (int nt = 0; nt < 2; ++nt)
        #pragma unroll
        for (int r = 0; r < 16; ++r) {
            int row = (r & 3) + 8 * (r >> 2) + rowhi;
            cr[nt][r] = c0[(size_t)(m0 + row) * HID + jcol[nt]];
        }

    const int rr = tid >> 3;       // staging: 8 threads per row (32 rows)
    const int q  = tid & 7;

    for (int t = 0; t < TST; ++t) {
        const _Float16* rb = hb + (size_t)((t + 2) % 3) * (BATCH * HID);
        _Float16*       wb = hb + (size_t)(t % 3) * (BATCH * HID);

        // ---- issue x loads first: their latency hides under the flag poll ----
        float4 x0, x1;
        {
            const float* xp = x + (size_t)(m0 + rr) * (TST * INSZ) + t * INSZ + q * 8;
            x0 = ((const float4*)xp)[0];
            x1 = ((const float4*)xp)[1];
        }
        if (t == 0) {
            u64 hv[16];
            #pragma unroll
            for (int u = 0; u < 16; ++u) {
                float4 f = *(const float4*)(h0 + (size_t)(m0 + rr) * HID + q * 4 + u * 32);
                hv[u] = cvt4_u64(f);
            }
            #pragma unroll
            for (int u = 0; u < 16; ++u)
                *(u64*)&As[rr][q * 4 + u * 32] = hv[u];
        } else {
            // ---- poll: lanes 0..31 each watch one (jb,w) wave flag.
            // Waves set flag = t at the end of step t-1. Watchdog: cap the
            // spin at 2^16 iterations (~20ms >> expected ~5us) so a latent
            // sync bug can never wedge the GPU.
            const unsigned tgt = (unsigned)t;
            int spins = 0;
            while (true) {
                unsigned v = tgt;
                if (lane < 32)
                    v = __hip_atomic_load(flg + lane,
                                          __ATOMIC_RELAXED, __HIP_MEMORY_SCOPE_AGENT);
                if (__all((int)(v >= tgt))) break;
                if (++spins > (1 << 16)) break;   // watchdog (never in practice)
                __builtin_amdgcn_s_sleep(1);
            }
            __atomic_signal_fence(__ATOMIC_SEQ_CST);  // compiler fence: no hoist/sink
            // coherent (sc0 sc1) 8B loads from the MALL — data was acked at the
            // coherence point before each producer wave's flag was set.
            const u64* rbq = (const u64*)(rb + (size_t)(m0 + rr) * HID);
            u64 hv[16];
            #pragma unroll
            for (int u = 0; u < 16; ++u)
                hv[u] = __hip_atomic_load(&rbq[q + u * 8],
                                          __ATOMIC_RELAXED, __HIP_MEMORY_SCOPE_AGENT);
            #pragma unroll
            for (int u = 0; u < 16; ++u)
                *(u64*)&As[rr][q * 4 + u * 32] = hv[u];
        }
        *(f16x8*)&As[rr][512 + q * 8] = cvt8(x0, x1);   // x_t -> k 512..575
        __syncthreads();   // staging join (the only barrier per step)

        // ---- MFMA: 36 k-tiles, 1 A-read feeds both n-tiles ----
        f32x16 acc[2];
        #pragma unroll
        for (int i = 0; i < 16; ++i) { acc[0][i] = 0.0f; acc[1][i] = 0.0f; }
        #pragma unroll
        for (int kt = 0; kt < 36; ++kt) {
            f16x8 af = *(const f16x8*)&As[l31][kt * 16 + khalf];
            acc[0] = __builtin_amdgcn_mfma_f32_32x32x16_f16(af, bfr[0][kt], acc[0], 0, 0, 0);
            acc[1] = __builtin_amdgcn_mfma_f32_32x32x16_f16(af, bfr[1][kt], acc[1], 0, 0, 0);
        }

        // ---- epilogue: DPP gate combine (VALU, no DS), c/h update, 8B stores ----
        #pragma unroll
        for (int nt = 0; nt < 2; ++nt) {
            #pragma unroll
            for (int r = 0; r < 16; ++r) {
                float v = acc[nt][r] + bsv[nt];
                float e = __expf(-s * v);
                float act = s * fast_rcp(1.0f + e) - (s - 1.0f);   // sigmoid or tanh
                float fu = dpp_f<0xB1>(act);   // quad xor1: f
                float gu = dpp_f<0x4E>(act);   // quad xor2: g
                float ou = dpp_f<0x1B>(act);   // quad xor3: o
                float cn = fu * cr[nt][r] + act * gu;
                cr[nt][r] = cn;
                float hn = ou * tanh_f(cn);
                unsigned hu = (unsigned)__builtin_bit_cast(unsigned short, (_Float16)hn);
                unsigned pk = hu | (dpp_u<0x104>(hu) << 16);          // <- lane+4
                u64 v4 = (u64)pk | ((u64)dpp_u<0x108>(pk) << 32);     // <- lane+8
                if ((l31 & 15) == 0) {
                    int row = (r & 3) + 8 * (r >> 2) + rowhi;
                    __hip_atomic_store((u64*)&wb[(size_t)(m0 + row) * HID + jcol[nt]],
                                       v4, __ATOMIC_RELAXED, __HIP_MEMORY_SCOPE_AGENT);
                }
            }
        }

        // ---- per-wave release: drain own stores, publish own flag.
        // No block barrier here: the poll (all 32 flags >= t+1) is the
        // LDS-reuse token for the next iteration's staging writes. ----
        asm volatile("s_waitcnt vmcnt(0)" ::: "memory");
        if (lane == 0)
            __hip_atomic_store(flg + (jb * 4 + w), (unsigned)(t + 1),
                               __ATOMIC_RELAXED, __HIP_MEMORY_SCOPE_AGENT);
    }
}

// ---------------- final linear: preds = hT @ W_lin^T + b_lin ----------------
__global__ __launch_bounds__(256) void final_kernel(
    const _Float16* __restrict__ h, const float* __restrict__ Wl,
    const float* __restrict__ bl, float* __restrict__ out)
{
    int i = blockIdx.x * 256 + threadIdx.x;
    if (i >= BATCH * NCLS) return;
    int b = i / NCLS, c = i - b * NCLS;
    const f16x8* hp = (const f16x8*)(h + (size_t)b * HID);
    const float4* wp = (const float4*)(Wl + (size_t)c * HID);
    float sacc = bl[c];
    #pragma unroll 4
    for (int k8 = 0; k8 < HID / 8; ++k8) {
        f16x8 hv = hp[k8];
        float4 w0 = wp[2 * k8], w1 = wp[2 * k8 + 1];
        sacc += (float)hv[0] * w0.x + (float)hv[1] * w0.y +
                (float)hv[2] * w0.z + (float)hv[3] * w0.w +
                (float)hv[4] * w1.x + (float)hv[5] * w1.y +
                (float)hv[6] * w1.z + (float)hv[7] * w1.w;
    }
    out[i] = sacc;
}

extern "C" void kernel_launch(void* const* d_in, const int* in_sizes, int n_in,
                              void* d_out, int out_size, void* d_ws, size_t ws_size,
                              hipStream_t stream)
{
    const float* x    = (const float*)d_in[0];
    const float* h0   = (const float*)d_in[1];
    const float* c0   = (const float*)d_in[2];
    const float* Wih  = (const float*)d_in[3];
    const float* Whh  = (const float*)d_in[4];
    const float* bih  = (const float*)d_in[5];
    const float* bhh  = (const float*)d_in[6];
    const float* Wlin = (const float*)d_in[7];
    const float* blin = (const float*)d_in[8];
    float* out = (float*)d_out;

    unsigned* bar = (unsigned*)d_ws;                   // 32 groups x 32 wave-flags
    _Float16* hb  = (_Float16*)((char*)d_ws + 8192);   // 3 x 1 MB h buffers

    hipMemsetAsync(d_ws, 0, 8192, stream);             // zero release flags

    // 256 blocks, 1/CU (launch_bounds(256,1), 37KB LDS) -> all co-resident.
    lstm_persist<<<256, 256, 0, stream>>>(x, h0, c0, Wih, Whh, bih, bhh, hb, bar);

    // step t=255 wrote buffer (255 % 3) == 0 -> hb
    final_kernel<<<(BATCH * NCLS + 255) / 256, 256, 0, stream>>>(hb, Wlin, blin, out);
}